// Round 13
// baseline (250.941 us; speedup 1.0000x reference)
//
#include <hip/hip_runtime.h>

#define NT 256   // 4 independent waves per block; no barriers anywhere

typedef float v2f __attribute__((ext_vector_type(2)));
typedef float f4u __attribute__((ext_vector_type(4), aligned(4)));

// Gaussian(sigma=1.5, 11 taps), normalized; 0 outside [0,10]
__device__ __forceinline__ constexpr float Wj(int j) {
    return (j < 0 || j > 10) ? 0.f :
           (j == 0 || j == 10) ? 0.00102838f :
           (j == 1 || j == 9)  ? 0.00759878f :
           (j == 2 || j == 8)  ? 0.03600077f :
           (j == 3 || j == 7)  ? 0.10936069f :
           (j == 4 || j == 6)  ? 0.21300553f : 0.26601172f;
}

// Sliding-window MS-SSIM level kernel.
// Round-13 revision: DEPTH-2 software pipeline. Two register row-windows
// (A/B ping-pong). While row h (buffer P) is consumed, row h+1 (buffer ~P)
// is in flight, and row h+2 is issued into P immediately after consumption.
// The s_waitcnt for a buffer therefore sits one FULL phase (~500+ cyc) after
// its issue, covering L2 latency (and most of HBM with 3 waves/SIMD).
// 22-phase static unroll keeps ring slots AND buffer parity compile-time.
__global__ __attribute__((amdgpu_flat_work_group_size(NT, NT), amdgpu_waves_per_eu(2, 4)))
void msssim_slide_kernel(
    const float* __restrict__ x1, const float* __restrict__ x2, int strideIn,
    float* __restrict__ p1, float* __restrict__ p2, int strideOut,
    float* __restrict__ accCS, float* __restrict__ accSSIM,
    int H, int W, int strips, int chunksY, int chunkRows, int padded)
{
    const int t = threadIdx.x;
    const int lane = t & 63;

    // ---- bijective XCD swizzle (gridDim.x always a multiple of 8) ----
    const int cpx = gridDim.x >> 3;
    const int lb = (blockIdx.x & 7) * cpx + (blockIdx.x >> 3);
    const int wid = lb * (NT / 64) + (t >> 6);

    const int perImg = strips * chunksY;
    const int img = wid / perImg;
    const int rem = wid - img * perImg;
    const int strip = rem / chunksY;           // vertical-first within image
    const int chunk = rem % chunksY;
    const int cc = strip * 64 + lane;          // my output column
    const int r0 = chunk * chunkRows;          // first output row
    const int hEnd = r0 + chunkRows + 5;       // last input row + 1
    const bool edge = (!padded) && (strip == 0 || strip == strips - 1);
    const bool laneValid = (cc < W);
    const bool doPool = (p1 != nullptr);
    const int Wp = W >> 1;

    const size_t imgIn = (size_t)img * H * strideIn;
    const float* __restrict__ base1 = x1 + imgIn;
    const float* __restrict__ base2 = x2 + imgIn;
    const size_t imgOut = doPool ? (size_t)img * (H >> 1) * strideOut : 0;
    float* __restrict__ q1 = doPool ? (p1 + imgOut) : nullptr;
    float* __restrict__ q2 = doPool ? (p2 + imgOut) : nullptr;

    float nA1[12], nA2[12], nB1[12], nB2[12];  // ping-pong row windows
    v2f psd[11], psq[11];       // pending V-outputs ring (assign-first lifecycle)
    float prs1 = 0.f, prs2 = 0.f;  // pool row-pair partial sums
    float cs_s = 0.f, ssim_s = 0.f;

    auto loadRow = [&](int h, float (&d1)[12], float (&d2)[12]) {
        if (h < 0 || h >= H || !laneValid) return;   // zero-pad rows / idle lanes
        const float* __restrict__ r1 = base1 + (size_t)h * strideIn;
        const float* __restrict__ r2 = base2 + (size_t)h * strideIn;
        if (!edge) {
            const f4u* a4 = reinterpret_cast<const f4u*>(r1 + (cc - 5));
            const f4u* b4 = reinterpret_cast<const f4u*>(r2 + (cc - 5));
            f4u A0 = a4[0], A1 = a4[1], A2 = a4[2];
            f4u B0 = b4[0], B1 = b4[1], B2 = b4[2];
#pragma unroll
            for (int j = 0; j < 4; ++j) { d1[j] = A0[j]; d1[4 + j] = A1[j]; d1[8 + j] = A2[j]; }
#pragma unroll
            for (int j = 0; j < 4; ++j) { d2[j] = B0[j]; d2[4 + j] = B1[j]; d2[8 + j] = B2[j]; }
        } else {
            // clamped + masked scalar path (level-0 image column borders)
#pragma unroll
            for (int j = 0; j < 12; ++j) {
                int col = cc + j - 5;
                int cl = col < 0 ? 0 : (col > W - 1 ? W - 1 : col);
                float a = r1[cl], b = r2[cl];
                bool ok = (col >= 0) && (col < W);
                d1[j] = ok ? a : 0.f;
                d2[j] = ok ? b : 0.f;
            }
        }
    };

    // prologue: rows r0-5 (buffer A) and r0-4 (buffer B) in flight
    loadRow(r0 - 5, nA1, nA2);
    loadRow(r0 - 4, nB1, nB2);

    const float C1 = 0.0001f, C2 = 0.0009f;

    for (int hb = r0 - 5; hb < hEnd; hb += 22) {
#pragma unroll
        for (int pp = 0; pp < 22; ++pp) {
            const int h = hb + pp;
            if (h < hEnd) {
                const int p = pp % 11;                       // ring phase
                float (&x1w)[12] = (pp & 1) ? nB1 : nA1;     // compile-time parity
                float (&x2w)[12] = (pp & 1) ? nB2 : nA2;

                // ---- 1. consume buffered row h: H-filter 4 moments ----
                v2f acc_sd = (v2f){0.f, 0.f}, acc_sq = (v2f){0.f, 0.f};
                const bool rv = (h >= 0) && (h < H);
                if (rv) {
                    if (doPool && h >= r0 && h < r0 + chunkRows) {
                        float ra = x1w[5] + x1w[6];   // cols cc, cc+1
                        float rb = x2w[5] + x2w[6];
                        if ((h & 1) == 0) { prs1 = ra; prs2 = rb; }
                        else if (!(lane & 1) && laneValid) {
                            size_t po = (size_t)(h >> 1) * strideOut + (cc >> 1);
                            q1[po] = 0.25f * (prs1 + ra);
                            q2[po] = 0.25f * (prs2 + rb);
                            // zero halos of the padded next-level image
                            if (cc == 0) {
                                *(f4u*)&q1[po - 8] = (f4u){0.f, 0.f, 0.f, 0.f};
                                *(f4u*)&q1[po - 4] = (f4u){0.f, 0.f, 0.f, 0.f};
                                *(f4u*)&q2[po - 8] = (f4u){0.f, 0.f, 0.f, 0.f};
                                *(f4u*)&q2[po - 4] = (f4u){0.f, 0.f, 0.f, 0.f};
                            }
                            if ((cc >> 1) == Wp - 1) {
#pragma unroll
                                for (int j = 1; j <= 8; ++j) { q1[po + j] = 0.f; q2[po + j] = 0.f; }
                            }
                        }
                    }
#pragma unroll
                    for (int j = 0; j < 11; ++j) {
                        // {s, d} = {x1+x2, x1-x2} in ONE packed fma: fma({1,-1}, x2, x1)
                        v2f xx1 = {x1w[j], x1w[j]};
                        v2f xx2 = {x2w[j], x2w[j]};
                        v2f sd = __builtin_elementwise_fma((v2f){1.f, -1.f}, xx2, xx1);
                        v2f w2 = {Wj(j), Wj(j)};
                        acc_sd = __builtin_elementwise_fma(w2, sd, acc_sd);
                        acc_sq = __builtin_elementwise_fma(w2, sd * sd, acc_sq);
                    }
                }
                // ---- 2. issue row h+2 into the just-consumed buffer ----
                if (h + 2 < hEnd) loadRow(h + 2, x1w, x2w);
                // ---- 3. V-ring update: row h feeds outputs h-5 .. h+5 ----
#pragma unroll
                for (int k = 0; k < 11; ++k) {
                    const int slot = (p + 5 - k + 11) % 11;
                    v2f w2 = {Wj(k), Wj(k)};
                    if (k == 0) {
                        psd[slot] = w2 * acc_sd;
                        psq[slot] = w2 * acc_sq;
                    } else {
                        psd[slot] = __builtin_elementwise_fma(w2, acc_sd, psd[slot]);
                        psq[slot] = __builtin_elementwise_fma(w2, acc_sq, psq[slot]);
                    }
                }
                // ---- 4. emit completed output row o = h-5 ----
                const int o = h - 5;
                if (o >= r0) {
                    const int es = (p + 6) % 11;
                    v2f m2 = psd[es] * psd[es];      // {Sm^2, Dm^2}
                    v2f t1 = psq[es] - m2;           // {SSm-Sm^2, DDm-Dm^2}
                    float num_cs = 0.5f * (t1.x - t1.y) + C2;   // 2*sigma12 + C2
                    float den_cs = 0.5f * (t1.x + t1.y) + C2;   // sig1+sig2 + C2
                    float num_ss = 0.5f * (m2.x - m2.y) + C1;   // 2*mu12 + C1
                    float den_ss = 0.5f * (m2.x + m2.y) + C1;   // mu1^2+mu2^2 + C1
                    float cs = num_cs / den_cs;
                    float ss = num_ss * cs / den_ss;
                    if (laneValid) { cs_s += cs; ssim_s += ss; }
                }
            }
        }
    }

    // ---- wave reduction -> 2 atomics per wave ----
#pragma unroll
    for (int off = 32; off > 0; off >>= 1) {
        cs_s += __shfl_down(cs_s, off);
        ssim_s += __shfl_down(ssim_s, off);
    }
    if (lane == 0) {
        atomicAdd(&accCS[img], cs_s);
        atomicAdd(&accSSIM[img], ssim_s);
    }
}

// acc layout: CS sums at acc[l*48 + img]; SSIM sums at acc[256 + l*48 + img]
__global__ void finalize_kernel(const float* __restrict__ acc, float* __restrict__ out) {
    __shared__ float vals[16];
    int t = threadIdx.x;
    if (t < 16) {
        const float w[5] = {0.0448f, 0.2856f, 0.3001f, 0.2363f, 0.1333f};
        float v = 1.f;
#pragma unroll
        for (int l = 0; l < 5; ++l) {
            int Hl = 512 >> l;
            float denom = 3.f * (float)Hl * (float)Hl;
            const float* src = (l < 4) ? (acc + l * 48) : (acc + 256 + l * 48);
            float m = src[3 * t] + src[3 * t + 1] + src[3 * t + 2];
            m = m / denom;
            m = fmaxf(m, 0.f);
            v *= powf(m, w[l]);
        }
        vals[t] = v;
    }
    __syncthreads();
    if (t == 0) {
        float s = 0.f;
        for (int i = 0; i < 16; ++i) s += vals[i];
        out[0] = s / 16.f;
    }
}

extern "C" void kernel_launch(void* const* d_in, const int* in_sizes, int n_in,
                              void* d_out, int out_size, void* d_ws, size_t ws_size,
                              hipStream_t stream) {
    const float* img1 = (const float*)d_in[0];
    const float* img2 = (const float*)d_in[1];
    float* out = (float*)d_out;
    float* ws = (float*)d_ws;

    float* acc = ws;
    size_t off = 512;

    // level arrays: padded stride Wl+16, pointer offset +8 (column halo)
    float* a1[5];
    float* a2[5];
    int strideL[5];
    a1[0] = (float*)img1; a2[0] = (float*)img2; strideL[0] = 512;
    for (int l = 1; l < 5; ++l) {
        int Hl = 512 >> l;
        strideL[l] = Hl + 16;
        a1[l] = ws + off + 8; off += (size_t)48 * Hl * strideL[l];
    }
    for (int l = 1; l < 5; ++l) {
        int Hl = 512 >> l;
        a2[l] = ws + off + 8; off += (size_t)48 * Hl * strideL[l];
    }

    hipMemsetAsync(acc, 0, 512 * sizeof(float), stream);

    for (int l = 0; l < 5; ++l) {
        int Hl = 512 >> l;
        int strips = (Hl + 63) / 64;                    // 8,4,2,1,1
        int chunkRows = (l == 0) ? 64 : (l == 1 ? 16 : 8);
        int chunksY = Hl / chunkRows;
        int waves = 48 * strips * chunksY;
        int blocks = waves / (NT / 64);                 // always % 8 == 0
        float* pp1 = (l < 4) ? a1[l + 1] : nullptr;
        float* pp2 = (l < 4) ? a2[l + 1] : nullptr;
        int so = (l < 4) ? strideL[l + 1] : 0;
        msssim_slide_kernel<<<blocks, NT, 0, stream>>>(
            a1[l], a2[l], strideL[l], pp1, pp2, so,
            acc + l * 48, acc + 256 + l * 48,
            Hl, Hl, strips, chunksY, chunkRows, l > 0 ? 1 : 0);
    }
    finalize_kernel<<<1, 64, 0, stream>>>(acc, out);
}

// Round 14
// 226.006 us; speedup vs baseline: 1.1103x; 1.1103x over previous
//
#include <hip/hip_runtime.h>

#define NT 256   // 4 independent waves per block; no barriers anywhere

typedef float v2f __attribute__((ext_vector_type(2)));
typedef float f4u __attribute__((ext_vector_type(4), aligned(4)));

// Gaussian(sigma=1.5, 11 taps), normalized; 0 outside [0,10]
__device__ __forceinline__ constexpr float Wj(int j) {
    return (j < 0 || j > 10) ? 0.f :
           (j == 0 || j == 10) ? 0.00102838f :
           (j == 1 || j == 9)  ? 0.00759878f :
           (j == 2 || j == 8)  ? 0.03600077f :
           (j == 3 || j == 7)  ? 0.10936069f :
           (j == 4 || j == 6)  ? 0.21300553f : 0.26601172f;
}

// Sliding-window MS-SSIM level kernel, depth-2 pipeline, SLIM body:
//  - template<EDGE>: interior dispatch has only the vector load path
//    (edge strips of L0 go to a separate small dispatch)
//  - halo zeroing done by one hipMemsetAsync of the whole ws region
//  - pool save/write selected by compile-time phase parity (r0 even)
//  - emit uses v_rcp_f32 (rel err ~2e-7, threshold 3.2e-3)
template<bool EDGE>
__global__ __attribute__((amdgpu_flat_work_group_size(NT, NT), amdgpu_waves_per_eu(2, 4)))
void msssim_slide(
    const float* __restrict__ x1, const float* __restrict__ x2, int strideIn,
    float* __restrict__ p1, float* __restrict__ p2, int strideOut,
    float* __restrict__ accCS, float* __restrict__ accSSIM,
    int H, int W, int stripBase, int stripStep, int nStrips,
    int chunksY, int chunkRows)
{
    const int t = threadIdx.x;
    const int lane = t & 63;

    // ---- bijective XCD swizzle (gridDim.x always a multiple of 8) ----
    const int cpx = gridDim.x >> 3;
    const int lb = (blockIdx.x & 7) * cpx + (blockIdx.x >> 3);
    const int wid = lb * (NT / 64) + (t >> 6);

    const int perImg = nStrips * chunksY;
    const int img = wid / perImg;
    const int rem = wid - img * perImg;
    const int sidx = rem / chunksY;            // vertical-first within image
    const int chunk = rem - sidx * chunksY;
    const int strip = stripBase + sidx * stripStep;
    const int cc = strip * 64 + lane;          // my output column
    const int r0 = chunk * chunkRows;          // first output row (EVEN)
    const int hEnd = r0 + chunkRows + 5;       // last input row + 1
    const bool laneValid = (cc < W);
    const bool doPool = (p1 != nullptr);

    const size_t imgIn = (size_t)img * H * strideIn;
    const float* __restrict__ base1 = x1 + imgIn;
    const float* __restrict__ base2 = x2 + imgIn;
    const size_t imgOut = doPool ? (size_t)img * (H >> 1) * strideOut : 0;
    float* __restrict__ q1 = doPool ? (p1 + imgOut) : nullptr;
    float* __restrict__ q2 = doPool ? (p2 + imgOut) : nullptr;

    float nA1[12], nA2[12], nB1[12], nB2[12];  // ping-pong row windows
    v2f psd[11], psq[11];       // pending V-outputs ring (assign-first lifecycle)
    float prs1 = 0.f, prs2 = 0.f;  // pool row-pair partial sums
    float cs_s = 0.f, ssim_s = 0.f;

    auto loadRow = [&](int h, float (&d1)[12], float (&d2)[12]) {
        if (h < 0 || h >= H || !laneValid) return;   // zero-pad rows / idle lanes
        const float* __restrict__ r1 = base1 + (size_t)h * strideIn;
        const float* __restrict__ r2 = base2 + (size_t)h * strideIn;
        if constexpr (!EDGE) {
            const f4u* a4 = reinterpret_cast<const f4u*>(r1 + (cc - 5));
            const f4u* b4 = reinterpret_cast<const f4u*>(r2 + (cc - 5));
            f4u A0 = a4[0], A1 = a4[1], A2 = a4[2];
            f4u B0 = b4[0], B1 = b4[1], B2 = b4[2];
#pragma unroll
            for (int j = 0; j < 4; ++j) { d1[j] = A0[j]; d1[4 + j] = A1[j]; d1[8 + j] = A2[j]; }
#pragma unroll
            for (int j = 0; j < 4; ++j) { d2[j] = B0[j]; d2[4 + j] = B1[j]; d2[8 + j] = B2[j]; }
        } else {
            // clamped + masked scalar path (level-0 image column borders)
#pragma unroll
            for (int j = 0; j < 12; ++j) {
                int col = cc + j - 5;
                int cl = col < 0 ? 0 : (col > W - 1 ? W - 1 : col);
                float a = r1[cl], b = r2[cl];
                bool ok = (col >= 0) && (col < W);
                d1[j] = ok ? a : 0.f;
                d2[j] = ok ? b : 0.f;
            }
        }
    };

    // prologue: rows r0-5 (buffer A) and r0-4 (buffer B) in flight
    loadRow(r0 - 5, nA1, nA2);
    loadRow(r0 - 4, nB1, nB2);

    const float C1 = 0.0001f, C2 = 0.0009f;

    // hb = r0-5 is ODD (r0 even) => pp even <-> h odd, pp odd <-> h even
    for (int hb = r0 - 5; hb < hEnd; hb += 22) {
#pragma unroll
        for (int pp = 0; pp < 22; ++pp) {
            const int h = hb + pp;
            if (h < hEnd) {
                const int p = pp % 11;                       // ring phase
                float (&x1w)[12] = (pp & 1) ? nB1 : nA1;     // compile-time parity
                float (&x2w)[12] = (pp & 1) ? nB2 : nA2;

                // ---- 1. consume buffered row h: H-filter 4 moments ----
                v2f acc_sd = (v2f){0.f, 0.f}, acc_sq = (v2f){0.f, 0.f};
                if (h >= 0 && h < H) {
                    if (doPool && h >= r0 && h < r0 + chunkRows) {
                        if constexpr (false) {}
                        if ((pp & 1) == 1) {                 // h EVEN: save pair
                            prs1 = x1w[5] + x1w[6];
                            prs2 = x2w[5] + x2w[6];
                        } else if (!(lane & 1) && laneValid) {  // h ODD: write pooled
                            size_t po = (size_t)(h >> 1) * strideOut + (cc >> 1);
                            q1[po] = 0.25f * (prs1 + x1w[5] + x1w[6]);
                            q2[po] = 0.25f * (prs2 + x2w[5] + x2w[6]);
                        }
                    }
#pragma unroll
                    for (int j = 0; j < 11; ++j) {
                        // {s, d} = {x1+x2, x1-x2} in ONE packed fma
                        v2f xx1 = {x1w[j], x1w[j]};
                        v2f xx2 = {x2w[j], x2w[j]};
                        v2f sd = __builtin_elementwise_fma((v2f){1.f, -1.f}, xx2, xx1);
                        v2f w2 = {Wj(j), Wj(j)};
                        acc_sd = __builtin_elementwise_fma(w2, sd, acc_sd);
                        acc_sq = __builtin_elementwise_fma(w2, sd * sd, acc_sq);
                    }
                }
                // ---- 2. issue row h+2 into the just-consumed buffer ----
                if (h + 2 < hEnd) loadRow(h + 2, x1w, x2w);
                // ---- 3. V-ring update: row h feeds outputs h-5 .. h+5 ----
#pragma unroll
                for (int k = 0; k < 11; ++k) {
                    const int slot = (p + 5 - k + 11) % 11;
                    v2f w2 = {Wj(k), Wj(k)};
                    if (k == 0) {
                        psd[slot] = w2 * acc_sd;
                        psq[slot] = w2 * acc_sq;
                    } else {
                        psd[slot] = __builtin_elementwise_fma(w2, acc_sd, psd[slot]);
                        psq[slot] = __builtin_elementwise_fma(w2, acc_sq, psq[slot]);
                    }
                }
                // ---- 4. emit completed output row o = h-5 (rcp-based) ----
                if (h - 5 >= r0) {
                    const int es = (p + 6) % 11;
                    v2f m2 = psd[es] * psd[es];      // {Sm^2, Dm^2}
                    v2f t1 = psq[es] - m2;           // {SSm-Sm^2, DDm-Dm^2}
                    float num_cs = 0.5f * (t1.x - t1.y) + C2;   // 2*sigma12 + C2
                    float den_cs = 0.5f * (t1.x + t1.y) + C2;   // sig1+sig2 + C2
                    float num_ss = 0.5f * (m2.x - m2.y) + C1;   // 2*mu12 + C1
                    float den_ss = 0.5f * (m2.x + m2.y) + C1;   // mu1^2+mu2^2 + C1
                    float cs = num_cs * __builtin_amdgcn_rcpf(den_cs);
                    float ss = num_ss * cs * __builtin_amdgcn_rcpf(den_ss);
                    if (laneValid) { cs_s += cs; ssim_s += ss; }
                }
            }
        }
    }

    // ---- wave reduction -> 2 atomics per wave ----
#pragma unroll
    for (int off = 32; off > 0; off >>= 1) {
        cs_s += __shfl_down(cs_s, off);
        ssim_s += __shfl_down(ssim_s, off);
    }
    if (lane == 0) {
        atomicAdd(&accCS[img], cs_s);
        atomicAdd(&accSSIM[img], ssim_s);
    }
}

// acc layout: CS sums at acc[l*48 + img]; SSIM sums at acc[256 + l*48 + img]
__global__ void finalize_kernel(const float* __restrict__ acc, float* __restrict__ out) {
    __shared__ float vals[16];
    int t = threadIdx.x;
    if (t < 16) {
        const float w[5] = {0.0448f, 0.2856f, 0.3001f, 0.2363f, 0.1333f};
        float v = 1.f;
#pragma unroll
        for (int l = 0; l < 5; ++l) {
            int Hl = 512 >> l;
            float denom = 3.f * (float)Hl * (float)Hl;
            const float* src = (l < 4) ? (acc + l * 48) : (acc + 256 + l * 48);
            float m = src[3 * t] + src[3 * t + 1] + src[3 * t + 2];
            m = m / denom;
            m = fmaxf(m, 0.f);
            v *= powf(m, w[l]);
        }
        vals[t] = v;
    }
    __syncthreads();
    if (t == 0) {
        float s = 0.f;
        for (int i = 0; i < 16; ++i) s += vals[i];
        out[0] = s / 16.f;
    }
}

extern "C" void kernel_launch(void* const* d_in, const int* in_sizes, int n_in,
                              void* d_out, int out_size, void* d_ws, size_t ws_size,
                              hipStream_t stream) {
    const float* img1 = (const float*)d_in[0];
    const float* img2 = (const float*)d_in[1];
    float* out = (float*)d_out;
    float* ws = (float*)d_ws;

    float* acc = ws;
    size_t off = 512;

    // level arrays: padded stride Wl+16, pointer offset +8 (column halo)
    float* a1[5];
    float* a2[5];
    int strideL[5];
    a1[0] = (float*)img1; a2[0] = (float*)img2; strideL[0] = 512;
    for (int l = 1; l < 5; ++l) {
        int Hl = 512 >> l;
        strideL[l] = Hl + 16;
        a1[l] = ws + off + 8; off += (size_t)48 * Hl * strideL[l];
    }
    for (int l = 1; l < 5; ++l) {
        int Hl = 512 >> l;
        a2[l] = ws + off + 8; off += (size_t)48 * Hl * strideL[l];
    }

    // zero accumulators AND all padded level halos in one memset (~36 MB)
    hipMemsetAsync(ws, 0, off * sizeof(float), stream);

    // ---- level 0: interior strips (vector path) + edge strips (clamp path) ----
    {
        int chunksY = 512 / 32;   // chunkRows 32
        int wavesI = 48 * 6 * chunksY;
        msssim_slide<false><<<wavesI / 4, NT, 0, stream>>>(
            a1[0], a2[0], 512, a1[1], a2[1], strideL[1],
            acc, acc + 256, 512, 512, /*stripBase*/1, /*step*/1, /*n*/6,
            chunksY, 32);
        int wavesE = 48 * 2 * chunksY;
        msssim_slide<true><<<wavesE / 4, NT, 0, stream>>>(
            a1[0], a2[0], 512, a1[1], a2[1], strideL[1],
            acc, acc + 256, 512, 512, /*stripBase*/0, /*step*/7, /*n*/2,
            chunksY, 32);
    }
    // ---- levels 1..4 (padded -> pure vector path) ----
    for (int l = 1; l < 5; ++l) {
        int Hl = 512 >> l;
        int strips = (Hl + 63) / 64;                    // 4,2,1,1
        int chunkRows = (l == 1) ? 16 : 8;
        int chunksY = Hl / chunkRows;
        int waves = 48 * strips * chunksY;
        float* pp1 = (l < 4) ? a1[l + 1] : nullptr;
        float* pp2 = (l < 4) ? a2[l + 1] : nullptr;
        int so = (l < 4) ? strideL[l + 1] : 0;
        msssim_slide<false><<<waves / 4, NT, 0, stream>>>(
            a1[l], a2[l], strideL[l], pp1, pp2, so,
            acc + l * 48, acc + 256 + l * 48,
            Hl, Hl, 0, 1, strips, chunksY, chunkRows);
    }
    finalize_kernel<<<1, 64, 0, stream>>>(acc, out);
}